// Round 5
// baseline (746.551 us; speedup 1.0000x reference)
//
#include <hip/hip_runtime.h>

#define N_NODES 100000
#define NEDGE   1600000
#define D       32

#define BSHIFT   7
#define BNODES   128                                  // nodes per bucket
#define NBUCKET  ((N_NODES + BNODES - 1) / BNODES)    // 782
#define NB_PAD   784
#define EPB      8192                                 // edges per block in bin pass
#define CBLK     ((NEDGE + EPB - 1) / EPB)            // 196
#define ASTRIDE  33                                   // padded LDS feature stride (floats)

// ---------- Kernel A: per-bucket edge histogram ----------
__global__ void bucket_hist_kernel(const int* __restrict__ dst, int* __restrict__ bucket_cnt) {
    __shared__ int h[NB_PAD];
    for (int i = threadIdx.x; i < NB_PAD; i += blockDim.x) h[i] = 0;
    __syncthreads();
    for (int e = blockIdx.x * blockDim.x + threadIdx.x; e < NEDGE; e += gridDim.x * blockDim.x)
        atomicAdd(&h[dst[e] >> BSHIFT], 1);
    __syncthreads();
    for (int i = threadIdx.x; i < NB_PAD; i += blockDim.x)
        if (h[i]) atomicAdd(&bucket_cnt[i], h[i]);
}

// ---------- Kernel B: exclusive scan of 784 bucket counts (1 block, 1024 thr) ----------
__global__ void bucket_scan_kernel(const int* __restrict__ bucket_cnt,
                                   int* __restrict__ bucket_off, int* __restrict__ bucket_cur) {
    __shared__ int s[1024];
    int tid = threadIdx.x;
    int v = (tid < NB_PAD) ? bucket_cnt[tid] : 0;
    s[tid] = v;
    __syncthreads();
    for (int o = 1; o < 1024; o <<= 1) {
        int t = (tid >= o) ? s[tid - o] : 0;
        __syncthreads();
        s[tid] += t;
        __syncthreads();
    }
    if (tid < NB_PAD) {
        int excl = s[tid] - v;
        bucket_off[tid] = excl;
        bucket_cur[tid] = excl;
    }
}

// ---------- Kernel C: bin edges into bucket-contiguous runs ----------
// packed: x = src | (dst_local << 17)   (src < 2^17, dst_local < 128), y = w bits
__global__ void bin_edges_kernel(const int* __restrict__ src, const int* __restrict__ dst,
                                 const float* __restrict__ w,
                                 int* __restrict__ bucket_cur, int2* __restrict__ binned) {
    __shared__ int cnt[NB_PAD];
    __shared__ int base[NB_PAD];
    int tid = threadIdx.x;
    for (int i = tid; i < NB_PAD; i += blockDim.x) cnt[i] = 0;
    __syncthreads();
    int e0 = blockIdx.x * EPB;
    for (int i = tid; i < EPB; i += blockDim.x) {
        int e = e0 + i;
        if (e < NEDGE) atomicAdd(&cnt[dst[e] >> BSHIFT], 1);
    }
    __syncthreads();
    for (int i = tid; i < NB_PAD; i += blockDim.x) {
        int c = cnt[i];
        base[i] = c ? atomicAdd(&bucket_cur[i], c) : 0;
        cnt[i] = 0;   // reuse as local cursor
    }
    __syncthreads();
    for (int i = tid; i < EPB; i += blockDim.x) {
        int e = e0 + i;
        if (e < NEDGE) {
            int d = dst[e];
            int b = d >> BSHIFT;
            int r = atomicAdd(&cnt[b], 1);
            binned[base[b] + r] = make_int2(src[e] | ((d & (BNODES - 1)) << 17),
                                            __float_as_int(w[e]));
        }
    }
}

// ---------- Kernel D: per-bucket SpMM with LDS accumulators ----------
// One block per bucket. Streams the bucket's edges (LDS-staged 256 at a time);
// 8 lanes per edge gather the 128B x-row and ds_add_f32 into acc[128][33]
// (stride 33 floats => bank (dl + 4c + j) % 32, spread by random dl).
// Output rows stream out fully coalesced.
__global__ __launch_bounds__(256) void spmm_bucket_kernel(
        const int* __restrict__ bucket_off, const int* __restrict__ bucket_cnt,
        const int2* __restrict__ binned, const float* __restrict__ x,
        float* __restrict__ out) {
    __shared__ float acc[BNODES * ASTRIDE];
    __shared__ int2 ebuf[256];
    int b = blockIdx.x;
    int tid = threadIdx.x;
    int start = bucket_off[b];
    int cntb  = bucket_cnt[b];

    for (int i = tid; i < BNODES * ASTRIDE; i += 256) acc[i] = 0.f;
    __syncthreads();

    const int c = tid & 7;
    for (int base0 = 0; base0 < cntb; base0 += 256) {
        int n = min(256, cntb - base0);
        if (tid < n) ebuf[tid] = binned[start + base0 + tid];
        __syncthreads();
        for (int k = tid >> 3; k < n; k += 32) {
            int2 p = ebuf[k];
            int   srcn = p.x & 0x1FFFF;
            int   dl   = (p.x >> 17) & (BNODES - 1);
            float wt   = __int_as_float(p.y);
            const float4 xv = *reinterpret_cast<const float4*>(&x[(long)srcn * D + c * 4]);
            float* a = &acc[dl * ASTRIDE + c * 4];
            atomicAdd(a + 0, wt * xv.x);
            atomicAdd(a + 1, wt * xv.y);
            atomicAdd(a + 2, wt * xv.z);
            atomicAdd(a + 3, wt * xv.w);
        }
        __syncthreads();
    }

    int node0 = b * BNODES;
    for (int i = tid; i < BNODES * 8; i += 256) {
        int row = i >> 3, cc = i & 7;
        int node = node0 + row;
        if (node < N_NODES) {
            const float* a = &acc[row * ASTRIDE + cc * 4];
            *reinterpret_cast<float4*>(&out[(long)node * D + cc * 4]) =
                make_float4(a[0], a[1], a[2], a[3]);
        }
    }
}

// ---------- fallback (atomic scatter) if ws too small ----------
__global__ void spmm_scatter_kernel(const int* __restrict__ src, const int* __restrict__ dst,
                                    const float* __restrict__ w, const float* __restrict__ x,
                                    float* __restrict__ out) {
    long gid = (long)blockIdx.x * blockDim.x + threadIdx.x;
    if (gid >= (long)NEDGE * 8) return;
    int e = (int)(gid >> 3);
    int c = (int)(gid & 7);
    int s = src[e], d = dst[e];
    float wt = w[e];
    const float4 xv = *reinterpret_cast<const float4*>(&x[(long)s * D + c * 4]);
    float* o = &out[(long)d * D + c * 4];
    atomicAdd(o + 0, wt * xv.x);
    atomicAdd(o + 1, wt * xv.y);
    atomicAdd(o + 2, wt * xv.z);
    atomicAdd(o + 3, wt * xv.w);
}

extern "C" void kernel_launch(void* const* d_in, const int* in_sizes, int n_in,
                              void* d_out, int out_size, void* d_ws, size_t ws_size,
                              hipStream_t stream) {
    const float* x    = (const float*)d_in[0];
    const int*   esrc = (const int*)d_in[1];
    const int*   edst = (const int*)d_in[2];
    const float* ew   = (const float*)d_in[3];
    float* out = (float*)d_out;

    char* ws = (char*)d_ws;
    const size_t y_bytes = (size_t)N_NODES * D * sizeof(float);   // 12.8 MB
    const size_t e_sw    = (size_t)NEDGE * sizeof(int2);          // 12.8 MB
    const size_t b_ints  = (size_t)NB_PAD * sizeof(int);

    size_t o = 0;
    float* y          = (float*)(ws + o); o += y_bytes;
    int2*  binned     = (int2*) (ws + o); o += e_sw;              // live through both layers
    int*   bucket_cnt = (int*)  (ws + o); o += b_ints;
    int*   bucket_off = (int*)  (ws + o); o += b_ints;
    int*   bucket_cur = (int*)  (ws + o); o += b_ints;

    if (ws_size < o) {
        hipMemsetAsync(y, 0, y_bytes, stream);
        hipMemsetAsync(out, 0, y_bytes, stream);
        const long total = (long)NEDGE * 8;
        const int blocks = (int)((total + 255) / 256);
        spmm_scatter_kernel<<<blocks, 256, 0, stream>>>(esrc, edst, ew, x, y);
        spmm_scatter_kernel<<<blocks, 256, 0, stream>>>(esrc, edst, ew, y, out);
        return;
    }

    hipMemsetAsync(bucket_cnt, 0, b_ints, stream);

    bucket_hist_kernel<<<256, 256, 0, stream>>>(edst, bucket_cnt);
    bucket_scan_kernel<<<1, 1024, 0, stream>>>(bucket_cnt, bucket_off, bucket_cur);
    bin_edges_kernel<<<CBLK, 256, 0, stream>>>(esrc, edst, ew, bucket_cur, binned);

    spmm_bucket_kernel<<<NBUCKET, 256, 0, stream>>>(bucket_off, bucket_cnt, binned, x, y);
    spmm_bucket_kernel<<<NBUCKET, 256, 0, stream>>>(bucket_off, bucket_cnt, binned, y, out);
}

// Round 6
// 138.898 us; speedup vs baseline: 5.3748x; 5.3748x over previous
//
#include <hip/hip_runtime.h>

#define N_NODES 100000
#define NEDGE   1600000
#define D       32

#define BSHIFT   7
#define BNODES   128                                  // nodes per bucket
#define NBUCKET  ((N_NODES + BNODES - 1) / BNODES)    // 782
#define NB_PAD   784
#define EPB      8192                                 // edges per block in bin pass
#define CBLK     ((NEDGE + EPB - 1) / EPB)            // 196
#define CAP      3072                                 // max edges/bucket for LDS path (mean 2048, sd~45)

// ---------- Kernel A: per-bucket edge histogram ----------
__global__ void bucket_hist_kernel(const int* __restrict__ dst, int* __restrict__ bucket_cnt) {
    __shared__ int h[NB_PAD];
    for (int i = threadIdx.x; i < NB_PAD; i += blockDim.x) h[i] = 0;
    __syncthreads();
    for (int e = blockIdx.x * blockDim.x + threadIdx.x; e < NEDGE; e += gridDim.x * blockDim.x)
        atomicAdd(&h[dst[e] >> BSHIFT], 1);
    __syncthreads();
    for (int i = threadIdx.x; i < NB_PAD; i += blockDim.x)
        if (h[i]) atomicAdd(&bucket_cnt[i], h[i]);
}

// ---------- Kernel B: exclusive scan of 784 bucket counts (1 block, 1024 thr) ----------
__global__ void bucket_scan_kernel(const int* __restrict__ bucket_cnt,
                                   int* __restrict__ bucket_off, int* __restrict__ bucket_cur) {
    __shared__ int s[1024];
    int tid = threadIdx.x;
    int v = (tid < NB_PAD) ? bucket_cnt[tid] : 0;
    s[tid] = v;
    __syncthreads();
    for (int o = 1; o < 1024; o <<= 1) {
        int t = (tid >= o) ? s[tid - o] : 0;
        __syncthreads();
        s[tid] += t;
        __syncthreads();
    }
    if (tid < NB_PAD) {
        int excl = s[tid] - v;
        bucket_off[tid] = excl;
        bucket_cur[tid] = excl;
    }
}

// ---------- Kernel C: bin edges into bucket-contiguous runs ----------
// packed: x = src | (dst_local << 17)   (src < 2^17, dst_local < 128), y = w bits
__global__ void bin_edges_kernel(const int* __restrict__ src, const int* __restrict__ dst,
                                 const float* __restrict__ w,
                                 int* __restrict__ bucket_cur, int2* __restrict__ binned) {
    __shared__ int cnt[NB_PAD];
    __shared__ int base[NB_PAD];
    int tid = threadIdx.x;
    for (int i = tid; i < NB_PAD; i += blockDim.x) cnt[i] = 0;
    __syncthreads();
    int e0 = blockIdx.x * EPB;
    for (int i = tid; i < EPB; i += blockDim.x) {
        int e = e0 + i;
        if (e < NEDGE) atomicAdd(&cnt[dst[e] >> BSHIFT], 1);
    }
    __syncthreads();
    for (int i = tid; i < NB_PAD; i += blockDim.x) {
        int c = cnt[i];
        base[i] = c ? atomicAdd(&bucket_cur[i], c) : 0;
        cnt[i] = 0;   // reuse as local cursor
    }
    __syncthreads();
    for (int i = tid; i < EPB; i += blockDim.x) {
        int e = e0 + i;
        if (e < NEDGE) {
            int d = dst[e];
            int b = d >> BSHIFT;
            int r = atomicAdd(&cnt[b], 1);
            binned[base[b] + r] = make_int2(src[e] | ((d & (BNODES - 1)) << 17),
                                            __float_as_int(w[e]));
        }
    }
}

// ---------- Kernel D: per-bucket CSR slice build (coalesced out) ----------
__global__ void build_csr_kernel(const int* __restrict__ bucket_off, const int* __restrict__ bucket_cnt,
                                 const int2* __restrict__ binned,
                                 int2* __restrict__ csr, int* __restrict__ off, int* __restrict__ deg) {
    __shared__ int2 stage[CAP];
    __shared__ int2 sorted[CAP];
    __shared__ int ndcnt[BNODES];
    __shared__ int ndoff[BNODES];
    __shared__ int s[BNODES];

    int b = blockIdx.x;
    int tid = threadIdx.x;
    int start = bucket_off[b];
    int cnt_b = bucket_cnt[b];
    bool fast = (cnt_b <= CAP);

    if (tid < BNODES) ndcnt[tid] = 0;
    if (fast)
        for (int i = tid; i < cnt_b; i += blockDim.x) stage[i] = binned[start + i];
    __syncthreads();

    if (fast) {
        for (int i = tid; i < cnt_b; i += blockDim.x)
            atomicAdd(&ndcnt[(stage[i].x >> 17) & (BNODES - 1)], 1);
    } else {
        for (int i = tid; i < cnt_b; i += blockDim.x)
            atomicAdd(&ndcnt[(binned[start + i].x >> 17) & (BNODES - 1)], 1);
    }
    __syncthreads();

    int v = (tid < BNODES) ? ndcnt[tid] : 0;
    if (tid < BNODES) s[tid] = v;
    __syncthreads();
    for (int o = 1; o < BNODES; o <<= 1) {
        int t = (tid < BNODES && tid >= o) ? s[tid - o] : 0;
        __syncthreads();
        if (tid < BNODES) s[tid] += t;
        __syncthreads();
    }
    if (tid < BNODES) {
        ndoff[tid] = s[tid] - v;
        int node = b * BNODES + tid;
        if (node < N_NODES) {
            off[node] = start + ndoff[tid];
            deg[node] = v;
        }
        ndcnt[tid] = 0;   // reuse as cursor
    }
    __syncthreads();

    if (fast) {
        for (int i = tid; i < cnt_b; i += blockDim.x) {
            int2 p = stage[i];
            int dl = (p.x >> 17) & (BNODES - 1);
            int r = atomicAdd(&ndcnt[dl], 1);
            sorted[ndoff[dl] + r] = make_int2(p.x & 0x1FFFF, p.y);
        }
        __syncthreads();
        for (int i = tid; i < cnt_b; i += blockDim.x) csr[start + i] = sorted[i];
    } else {
        for (int i = tid; i < cnt_b; i += blockDim.x) {
            int2 p = binned[start + i];
            int dl = (p.x >> 17) & (BNODES - 1);
            int r = atomicAdd(&ndcnt[dl], 1);
            csr[start + ndoff[dl] + r] = make_int2(p.x & 0x1FFFF, p.y);
        }
    }
}

// ---------- gather SpMM (no atomics, register acc, 2-way unrolled) ----------
// 8 threads per node; each owns a float4 slice of the 32-wide feature row.
// All 8 lanes of a node-group read the SAME csr entry (broadcast); the two
// edges in flight give independent load chains to hide gather latency.
__global__ void spmm_gather_kernel(const int* __restrict__ off, const int* __restrict__ deg,
                                   const int2* __restrict__ csr_sw,
                                   const float* __restrict__ x, float* __restrict__ out) {
    int gid = blockIdx.x * blockDim.x + threadIdx.x;
    if (gid >= N_NODES * 8) return;
    int node = gid >> 3;
    int c    = gid & 7;
    int start = off[node];
    int len   = deg[node];
    float4 acc = {0.f, 0.f, 0.f, 0.f};
    int k = 0;
    for (; k + 2 <= len; k += 2) {
        int2 sw0 = csr_sw[start + k];
        int2 sw1 = csr_sw[start + k + 1];
        const float4 xv0 = *reinterpret_cast<const float4*>(&x[(long)sw0.x * D + c * 4]);
        const float4 xv1 = *reinterpret_cast<const float4*>(&x[(long)sw1.x * D + c * 4]);
        float w0 = __int_as_float(sw0.y);
        float w1 = __int_as_float(sw1.y);
        acc.x += w0 * xv0.x; acc.y += w0 * xv0.y; acc.z += w0 * xv0.z; acc.w += w0 * xv0.w;
        acc.x += w1 * xv1.x; acc.y += w1 * xv1.y; acc.z += w1 * xv1.z; acc.w += w1 * xv1.w;
    }
    if (k < len) {
        int2 sw = csr_sw[start + k];
        const float4 xv = *reinterpret_cast<const float4*>(&x[(long)sw.x * D + c * 4]);
        float wt = __int_as_float(sw.y);
        acc.x += wt * xv.x; acc.y += wt * xv.y; acc.z += wt * xv.z; acc.w += wt * xv.w;
    }
    *reinterpret_cast<float4*>(&out[(long)node * D + c * 4]) = acc;
}

// ---------- fallback (atomic scatter) if ws too small ----------
__global__ void spmm_scatter_kernel(const int* __restrict__ src, const int* __restrict__ dst,
                                    const float* __restrict__ w, const float* __restrict__ x,
                                    float* __restrict__ out) {
    long gid = (long)blockIdx.x * blockDim.x + threadIdx.x;
    if (gid >= (long)NEDGE * 8) return;
    int e = (int)(gid >> 3);
    int c = (int)(gid & 7);
    int s = src[e], d = dst[e];
    float wt = w[e];
    const float4 xv = *reinterpret_cast<const float4*>(&x[(long)s * D + c * 4]);
    float* o = &out[(long)d * D + c * 4];
    atomicAdd(o + 0, wt * xv.x);
    atomicAdd(o + 1, wt * xv.y);
    atomicAdd(o + 2, wt * xv.z);
    atomicAdd(o + 3, wt * xv.w);
}

extern "C" void kernel_launch(void* const* d_in, const int* in_sizes, int n_in,
                              void* d_out, int out_size, void* d_ws, size_t ws_size,
                              hipStream_t stream) {
    const float* x    = (const float*)d_in[0];
    const int*   esrc = (const int*)d_in[1];
    const int*   edst = (const int*)d_in[2];
    const float* ew   = (const float*)d_in[3];
    float* out = (float*)d_out;

    char* ws = (char*)d_ws;
    const size_t y_bytes = (size_t)N_NODES * D * sizeof(float);   // 12.8 MB (== binned bytes)
    const size_t n_ints  = (size_t)N_NODES * sizeof(int);         // 400 KB
    const size_t b_ints  = (size_t)NB_PAD * sizeof(int);
    const size_t e_sw    = (size_t)NEDGE * sizeof(int2);          // 12.8 MB

    size_t o = 0;
    float* y          = (float*)(ws + o); o += y_bytes;           // aliases `binned`
    int2*  csr        = (int2*) (ws + o); o += e_sw;
    int*   off        = (int*)  (ws + o); o += n_ints;
    int*   deg        = (int*)  (ws + o); o += n_ints;
    int*   bucket_cnt = (int*)  (ws + o); o += b_ints;
    int*   bucket_off = (int*)  (ws + o); o += b_ints;
    int*   bucket_cur = (int*)  (ws + o); o += b_ints;
    int2*  binned     = (int2*)y;   // reuse: binned dead once csr built, y live after

    if (ws_size < o) {
        hipMemsetAsync(y, 0, y_bytes, stream);
        hipMemsetAsync(out, 0, y_bytes, stream);
        const long total = (long)NEDGE * 8;
        const int blocks = (int)((total + 255) / 256);
        spmm_scatter_kernel<<<blocks, 256, 0, stream>>>(esrc, edst, ew, x, y);
        spmm_scatter_kernel<<<blocks, 256, 0, stream>>>(esrc, edst, ew, y, out);
        return;
    }

    hipMemsetAsync(bucket_cnt, 0, b_ints, stream);

    bucket_hist_kernel<<<256, 256, 0, stream>>>(edst, bucket_cnt);
    bucket_scan_kernel<<<1, 1024, 0, stream>>>(bucket_cnt, bucket_off, bucket_cur);
    bin_edges_kernel<<<CBLK, 256, 0, stream>>>(esrc, edst, ew, bucket_cur, binned);
    build_csr_kernel<<<NBUCKET, 256, 0, stream>>>(bucket_off, bucket_cnt, binned, csr, off, deg);

    const int gblocks = (N_NODES * 8 + 255) / 256;
    spmm_gather_kernel<<<gblocks, 256, 0, stream>>>(off, deg, csr, x, y);
    spmm_gather_kernel<<<gblocks, 256, 0, stream>>>(off, deg, csr, y, out);
}